// Round 7
// baseline (1039.636 us; speedup 1.0000x reference)
//
#include <hip/hip_runtime.h>
#include <hip/hip_bf16.h>
#include <cstdint>

typedef __attribute__((ext_vector_type(8))) short short8;
typedef __attribute__((ext_vector_type(4))) float float4v;
typedef __attribute__((ext_vector_type(16))) float f32x16;

#define LOG2E 1.44269504088896340736f
#define LN2   0.69314718055994530942f

#if __has_builtin(__builtin_amdgcn_exp2f)
__device__ __forceinline__ float fexp2(float x){ return __builtin_amdgcn_exp2f(x); }
#else
__device__ __forceinline__ float fexp2(float x){ return exp2f(x); }
#endif
#if __has_builtin(__builtin_amdgcn_logf)
__device__ __forceinline__ float flog2(float x){ return __builtin_amdgcn_logf(x); }
#else
__device__ __forceinline__ float flog2(float x){ return log2f(x); }
#endif

// hhat = log2(1 + 2^zhat); biases pre-scaled by log2e so GEMM on hhat yields
// the next zhat directly (ln2 * log2e == 1 cancels).
__device__ __forceinline__ float softplus_hat(float zh){
  return flog2(1.0f + fexp2(zh));
}

// softplus output > 0 -> truncation (RTZ) to bf16 is a 1-instr shift.
__device__ __forceinline__ unsigned short bf16_trunc(float f){
  return (unsigned short)(__builtin_bit_cast(unsigned int, f) >> 16);
}

// h tile layout (per 64-row tile): addr(m,c) = m*264 + (m>>2)*16 + c elems.
// (champion layout, unchanged; verified conflict-minimal for both the 32-row
// A-read pattern (8 dword-accesses/bank uniform = min) and the 32x32 C-write.)
#define HSTRIDE 264
#define MISTEP32 8576                   // 32*264 + 8*16 (32-row mi step)
#define HSIZE   (64 * 264 + 16 * 16)    // 17152 elems = 34304 B per tile

// ---------------------------------------------------------------------------
// Pre-pass: Wh [S,4,256,256] fp32 -> bf16 slabs Wt[s*4+l][kb][n][ki]
// (kb = k/32, ki = k%32). ki is 8-aligned for K=16 mfma steps too:
// k = step*16 + (lane>>5)*8 -> kb = step>>1, ki = (step&1)*16 + (lane>>5)*8.
// ---------------------------------------------------------------------------
__global__ void convert_wh(const float* __restrict__ Wh,
                           unsigned short* __restrict__ Wt){
  int e = blockIdx.x * 256 + threadIdx.x;          // 0 .. 2^21-1
  int n  = e & 255;
  int k  = (e >> 8) & 255;
  int sl = e >> 16;
  float v = Wh[e];
  __hip_bfloat16 h = __float2bfloat16(v);
  Wt[(sl << 16) + ((k >> 5) << 13) + (n << 5) + (k & 31)] =
      __builtin_bit_cast(unsigned short, h);
}

// 32x32x16: matrix-pipe efficiency 4061 vs 3378 FLOP/cyc for 16x16x32 (m119)
// -> 17% fewer matrix cycles for identical FLOPs.
__device__ __forceinline__ f32x16 bf16_mfma32(short8 a, short8 b, f32x16 c){
  return __builtin_amdgcn_mfma_f32_32x32x16_bf16(a, b, c, 0, 0, 0);
}

// layer-0 (K=3) for rows 4j..4j+3 of one 64-row tile, column c
__device__ __forceinline__ void l0_rows(
    unsigned short* __restrict__ ht, const float4v* __restrict__ c4,
    int j, int c, float w0, float w1, float w2, float bb)
{
  float4v x0 = c4[j*3+0], x1 = c4[j*3+1], x2 = c4[j*3+2];
  float z0 = fmaf(x0.z, w2, fmaf(x0.y, w1, fmaf(x0.x, w0, bb)));
  float z1 = fmaf(x1.y, w2, fmaf(x1.x, w1, fmaf(x0.w, w0, bb)));
  float z2 = fmaf(x2.x, w2, fmaf(x1.w, w1, fmaf(x1.z, w0, bb)));
  float z3 = fmaf(x2.w, w2, fmaf(x2.z, w1, fmaf(x2.y, w0, bb)));
  ht[(4*j+0)*HSTRIDE + j*16 + c] = bf16_trunc(softplus_hat(z0));
  ht[(4*j+1)*HSTRIDE + j*16 + c] = bf16_trunc(softplus_hat(z1));
  ht[(4*j+2)*HSTRIDE + j*16 + c] = bf16_trunc(softplus_hat(z2));
  ht[(4*j+3)*HSTRIDE + j*16 + c] = bf16_trunc(softplus_hat(z3));
}

// D-frag el (mi,ni,reg=q4*4+r): row = mi*32 + 8*q4 + r + 4*(lane>>5),
// col = wavecol + ni*32 + (lane&31). Writeback addr = lanebase
// [(lane&31)+wave*64+(lane>>5)*1072] + imm [ni*32 + q4*2144 + r*264 + mi*8576].
// softplus + write 4 els (one reg-quad) of the OTHER tile's acc per step.
__device__ __forceinline__ void sp32(const f32x16 (&acc)[2][2],
    unsigned short* __restrict__ cptr, int st)
{
  const int mi = st >> 3, ni = (st >> 2) & 1, q4 = st & 3;
  f32x16 v = acc[mi][ni];
  #pragma unroll
  for (int r = 0; r < 4; ++r)
    cptr[ni*32 + q4*2144 + r*264 + mi*MISTEP32] =
        bf16_trunc(softplus_hat(v[q4*4 + r]));
}

// softplus + output-dot of 4 els of the OTHER tile's acc (last layer);
// p slot = mi*16 + q4*4 + r (row identity; both ni fold into the same slot).
__device__ __forceinline__ void spdot32(const f32x16 (&acc)[2][2],
    const float (&wv)[2], float (&p)[32], int st)
{
  const int mi = st >> 3, ni = (st >> 2) & 1, q4 = st & 3;
  f32x16 v = acc[mi][ni];
  #pragma unroll
  for (int r = 0; r < 4; ++r)
    p[mi*16 + q4*4 + r] = fmaf(softplus_hat(v[q4*4 + r]), wv[ni],
                               p[mi*16 + q4*4 + r]);
}

// ---------------------------------------------------------------------------
// One phase = 16 K-steps (K=16 each). Per step: {4 mfma_32x32x16 + mem-issue}
// / {4 softplus els of the other tile} pinned by sched_barrier(0).
// A prefetch depth 1 step (LDS); B rotating 3-slot prefetch depth 3 steps,
// slot=(16*PH+st)%3 continuous across phases; st 13..15 prefetch the NEXT
// phase's st 0..2 from bn.
// ---------------------------------------------------------------------------
template<int PH, bool LOADN, class F>
__device__ __forceinline__ void mfma_phase(
    const unsigned short* __restrict__ bb,   // this phase's slab + lane offset
    const unsigned short* __restrict__ bn,   // next phase's slab + lane offset
    const unsigned short* __restrict__ aptr, // h tile + lane A-base
    short8 (&bq)[3][2], f32x16 (&acc)[2][2], F&& other)
{
  short8 a0[2], a1[2];
  #pragma unroll
  for (int mi = 0; mi < 2; ++mi)
    a0[mi] = *(const short8*)(aptr + mi * MISTEP32);

  #pragma unroll
  for (int st = 0; st < 16; ++st) {
    short8* cur = (st & 1) ? a1 : a0;
    short8* nxt = (st & 1) ? a0 : a1;
    const int slot = (16 * PH + st) % 3;           // compile-time (unrolled)
    acc[0][0] = bf16_mfma32(cur[0], bq[slot][0], acc[0][0]);
    acc[0][1] = bf16_mfma32(cur[0], bq[slot][1], acc[0][1]);
    acc[1][0] = bf16_mfma32(cur[1], bq[slot][0], acc[1][0]);
    acc[1][1] = bf16_mfma32(cur[1], bq[slot][1], acc[1][1]);
    if (st < 15) {                                 // A prefetch depth 1 (LDS)
      #pragma unroll
      for (int mi = 0; mi < 2; ++mi)
        nxt[mi] = *(const short8*)(aptr + (st + 1) * 16 + mi * MISTEP32);
    }
    if (st < 13) {                                 // B depth-3, this phase
      #pragma unroll
      for (int ni = 0; ni < 2; ++ni)
        bq[slot][ni] = *(const short8*)(bb + ((st + 3) >> 1) * 8192 +
                                        ni * 1024 + ((st + 3) & 1) * 16);
    } else if (LOADN) {                            // next phase's st 0..2
      #pragma unroll
      for (int ni = 0; ni < 2; ++ni)
        bq[slot][ni] = *(const short8*)(bn + ((st - 13) >> 1) * 8192 +
                                        ni * 1024 + ((st - 13) & 1) * 16);
    }
    __builtin_amdgcn_sched_barrier(0);
    other(st);                                     // 4 softplus els (VALU)
    __builtin_amdgcn_sched_barrier(0);
  }
}

// ---------------------------------------------------------------------------
// Fused MLP: one workgroup owns TWO 64-row tiles (128 rows) in anti-phase.
// Each phase: K-loop(tile X, layer l) with tile Y's softplus interleaved.
// 4 waves, wave tile 64m x 64n, one series/block, s = blk&7.
// LDS: 2 x 34304 B tiles + cbuf = 70 KB -> 2 blocks/CU.
// ---------------------------------------------------------------------------
__global__ __launch_bounds__(256, 2) void series_mlp(
    const float* __restrict__ coords,
    const float* __restrict__ W0, const float* __restrict__ b0,
    const float* __restrict__ bh,
    const float* __restrict__ Wout, const float* __restrict__ bout,
    const unsigned short* __restrict__ Wt,
    float* __restrict__ out)
{
  __shared__ __align__(16) unsigned short h_lds[2 * HSIZE];   // 68608 B
  __shared__ float cbuf[384];

  const int tid  = threadIdx.x;
  const int lane = tid & 63;
  const int wave = tid >> 6;
  const int s    = blockIdx.x & 7;           // series == XCD
  const int m0   = (blockIdx.x >> 3) * 128;  // 1563 m-blocks; tail tile1 dead

  const int l31  = lane & 31;
  const int lh   = lane >> 5;

  // coords for 128 rows (tail block: clamp index -> finite garbage, unwritten)
  {
    int i1 = m0 * 3 + tid;
    int i2 = i1 + 256;
    cbuf[tid] = coords[i1 < 599999 ? i1 : 599999];
    if (tid < 128) cbuf[tid + 256] = coords[i2 < 599999 ? i2 : 599999];
  }

  // layer-0 weights for this thread's column (shared by both tiles)
  const int c = tid;
  const float w0  = W0[(s * 3 + 0) * 256 + c] * LOG2E;
  const float w1  = W0[(s * 3 + 1) * 256 + c] * LOG2E;
  const float w2  = W0[(s * 3 + 2) * 256 + c] * LOG2E;
  const float bb0 = b0[s * 256 + c] * LOG2E;

  // B-frag lane base: col = wave*64 + ni*32 + l31, k-octet lh.
  const unsigned short* bbase0 =
      Wt + ((s << 2) << 16) + ((wave << 6) + l31) * 32 + (lh << 3);
  short8 bq[3][2];
  #pragma unroll
  for (int i = 0; i < 3; ++i)                 // slots 0..2 = steps 0..2
    #pragma unroll
    for (int ni = 0; ni < 2; ++ni)
      bq[i][ni] = *(const short8*)(bbase0 + (i >> 1) * 8192 + ni * 1024 +
                                   (i & 1) * 16);

  // bias/Wout preload (hoisted; L2-resident)
  const float* bh_s = bh + (s << 10);
  float bias_r[4][2];
  #pragma unroll
  for (int l = 0; l < 4; ++l)
    #pragma unroll
    for (int ni = 0; ni < 2; ++ni)
      bias_r[l][ni] = bh_s[l * 256 + (wave << 6) + ni * 32 + l31] * LOG2E;
  float wv[2];
  #pragma unroll
  for (int ni = 0; ni < 2; ++ni)
    wv[ni] = Wout[(s << 8) + (wave << 6) + ni * 32 + l31];

  // A-frag lane base: row l31 (skew (l31>>2)*16), k-octet lh.
  const unsigned short* aptrA =
      h_lds + l31 * HSTRIDE + (l31 >> 2) * 16 + (lh << 3);
  const unsigned short* aptrB = aptrA + HSIZE;
  // C-write lane base: +lh*1072 = 4-row offset under the skewed layout.
  unsigned short* cptrA = h_lds + (wave << 6) + l31 + lh * 1072;
  unsigned short* cptrB = cptrA + HSIZE;

  const float4v* c4 = (const float4v*)cbuf;

  __syncthreads();                      // cbuf ready
  #pragma unroll
  for (int j = 0; j < 16; ++j)          // layer 0, tile A (exposed prologue)
    l0_rows(h_lds, c4, j, c, w0, w1, w2, bb0);
  __syncthreads();                      // hA(0) ready

  f32x16 accA[2][2], accB[2][2];

#define INIT_ACC(ACC, LIDX)                                                   \
  {                                                                           \
    _Pragma("unroll")                                                         \
    for (int mi = 0; mi < 2; ++mi)                                            \
      _Pragma("unroll")                                                       \
      for (int ni = 0; ni < 2; ++ni) {                                        \
        float bv = bias_r[LIDX][ni];                                          \
        _Pragma("unroll")                                                     \
        for (int r = 0; r < 16; ++r) ACC[mi][ni][r] = bv;                     \
      }                                                                       \
  }

  const unsigned short* B0 = bbase0;
  const unsigned short* B1 = bbase0 + 65536;
  const unsigned short* B2 = bbase0 + 2 * 65536;
  const unsigned short* B3 = bbase0 + 3 * 65536;

  // P0: K(tA, l0) || layer-0 for tile B (one row-quad per step)
  INIT_ACC(accA, 0)
  mfma_phase<0, true>(B0, B0, aptrA, bq, accA, [&](int st){
    l0_rows(h_lds + HSIZE, c4 + 48, st, c, w0, w1, w2, bb0);
  });
  __syncthreads();                      // hB(0) ready

  // P1: K(tB, l0) || softplus(accA) -> hA(1)
  INIT_ACC(accB, 0)
  mfma_phase<1, true>(B0, B1, aptrB, bq, accB,
      [&](int st){ sp32(accA, cptrA, st); });
  __syncthreads();                      // hA(1) ready

  // P2: K(tA, l1) || softplus(accB) -> hB(1)
  INIT_ACC(accA, 1)
  mfma_phase<2, true>(B1, B1, aptrA, bq, accA,
      [&](int st){ sp32(accB, cptrB, st); });
  __syncthreads();                      // hB(1) ready

  // P3: K(tB, l1) || softplus(accA) -> hA(2)
  INIT_ACC(accB, 1)
  mfma_phase<3, true>(B1, B2, aptrB, bq, accB,
      [&](int st){ sp32(accA, cptrA, st); });
  __syncthreads();                      // hA(2) ready

  // P4: K(tA, l2) || softplus(accB) -> hB(2)
  INIT_ACC(accA, 2)
  mfma_phase<4, true>(B2, B2, aptrA, bq, accA,
      [&](int st){ sp32(accB, cptrB, st); });
  __syncthreads();                      // hB(2) ready

  // P5: K(tB, l2) || softplus(accA) -> hA(3)
  INIT_ACC(accB, 2)
  mfma_phase<5, true>(B2, B3, aptrB, bq, accB,
      [&](int st){ sp32(accA, cptrA, st); });
  __syncthreads();                      // hA(3) ready

  // P6: K(tA, l3) || softplus(accB) -> hB(3)
  INIT_ACC(accA, 3)
  mfma_phase<6, true>(B3, B3, aptrA, bq, accA,
      [&](int st){ sp32(accB, cptrB, st); });
  __syncthreads();                      // hB(3) ready

  // P7: K(tB, l3) || softplus+output-dot of accA
  INIT_ACC(accB, 3)
  float pA[32], pB[32];
  #pragma unroll
  for (int i = 0; i < 32; ++i) pA[i] = 0.f;
  mfma_phase<7, false>(B3, B3, aptrB, bq, accB,
      [&](int st){ spdot32(accA, wv, pA, st); });

  #pragma unroll
  for (int i = 0; i < 32; ++i) pB[i] = 0.f;
  #pragma unroll
  for (int st = 0; st < 16; ++st)       // tile B's dot (exposed epilogue)
    spdot32(accB, wv, pB, st);

  // cross-wave reduce: per tile 64 rows x 128 partials (stride-132 pad).
  // Row of p-slot (mi,q4,r) = mi*32+8q4+r (+4 for upper lane half).
  __syncthreads();                      // all P7 A-reads of hB done
  float* redA = (float*)h_lds;
  float* redB = (float*)(h_lds + HSIZE);
  const int rbase = lh * 528 + (wave << 5) + l31;   // 4h rows + partial col
  #pragma unroll
  for (int mi = 0; mi < 2; ++mi)
    #pragma unroll
    for (int q4 = 0; q4 < 4; ++q4)
      #pragma unroll
      for (int r = 0; r < 4; ++r) {
        const int sl = mi * 16 + q4 * 4 + r;
        const int mb = mi * 32 + q4 * 8 + r;
        redA[mb * 132 + rbase] = pA[sl];
        redB[mb * 132 + rbase] = pB[sl];
      }
  __syncthreads();

  {
    const int rowg = tid >> 1, half = tid & 1;
    const float* red = (rowg < 64) ? redA : redB;
    const float4v* rr = (const float4v*)&red[(rowg & 63) * 132 + half * 64];
    float4v a = rr[0];
    #pragma unroll
    for (int i = 1; i < 16; ++i) {
      float4v b = rr[i];
      a.x += b.x; a.y += b.y; a.z += b.z; a.w += b.w;
    }
    float hsum = (a.x + a.y) + (a.z + a.w);
    float tot = hsum + __shfl_xor(hsum, 1);
    if (half == 0) {
      int row = m0 + rowg;
      if (row < 200000)
        out[row * 8 + s] = fmaf(LN2, tot, bout[s]);  // undo log2-domain
    }
  }
#undef INIT_ACC
}

// ---------------------------------------------------------------------------
// Fallback (scratch-free), fp32 VALU — only if ws_size < 4 MiB.
// ---------------------------------------------------------------------------
__global__ __launch_bounds__(256) void series_mlp_slow(
    const float* __restrict__ coords,
    const float* __restrict__ W0, const float* __restrict__ b0,
    const float* __restrict__ Wh, const float* __restrict__ bh,
    const float* __restrict__ Wout, const float* __restrict__ bout,
    float* __restrict__ out)
{
  __shared__ float hh[64 * 256];
  __shared__ float cbuf[192];
  __shared__ float red[256];
  const int tid = threadIdx.x;
  const int s   = blockIdx.y;
  const int m0  = blockIdx.x * 64;

  if (tid < 192) cbuf[tid] = coords[m0 * 3 + tid];
  __syncthreads();
  {
    const float w0 = W0[(s * 3 + 0) * 256 + tid];
    const float w1 = W0[(s * 3 + 1) * 256 + tid];
    const float w2 = W0[(s * 3 + 2) * 256 + tid];
    const float bb = b0[s * 256 + tid];
    for (int m = 0; m < 64; ++m) {
      float z = fmaf(cbuf[m * 3 + 2], w2,
                fmaf(cbuf[m * 3 + 1], w1,
                fmaf(cbuf[m * 3 + 0], w0, bb)));
      hh[m * 256 + tid] = LN2 * softplus_hat(z * LOG2E);
    }
  }
  __syncthreads();

  for (int l = 0; l < 4; ++l) {
    const float* W = Wh + (((s << 2) + l) << 16);
    const float bb = bh[((s << 2) + l) * 256 + tid];
    float acc[64];
    #pragma unroll
    for (int m = 0; m < 64; ++m) acc[m] = bb;
    for (int kc = 0; kc < 64; ++kc) {
      float w0 = W[(kc * 4 + 0) * 256 + tid];
      float w1 = W[(kc * 4 + 1) * 256 + tid];
      float w2 = W[(kc * 4 + 2) * 256 + tid];
      float w3 = W[(kc * 4 + 3) * 256 + tid];
      #pragma unroll
      for (int m = 0; m < 64; ++m) {
        float4v hv = *(const float4v*)&hh[m * 256 + kc * 4];
        acc[m] = fmaf(hv.w, w3, fmaf(hv.z, w2,
                 fmaf(hv.y, w1, fmaf(hv.x, w0, acc[m]))));
      }
    }
    __syncthreads();
    #pragma unroll
    for (int m = 0; m < 64; ++m)
      hh[m * 256 + tid] = LN2 * softplus_hat(acc[m] * LOG2E);
    __syncthreads();
  }
  {
    const int m = tid >> 2, qq = tid & 3;
    const float* wv = Wout + (s << 8);
    float sum = 0.f;
    for (int i = 0; i < 16; ++i) {
      int kk = (qq << 6) + ((((tid & 15) + i) << 2) & 63);
      float4v hv = *(const float4v*)&hh[m * 256 + kk];
      sum += hv.x * wv[kk] + hv.y * wv[kk + 1] + hv.z * wv[kk + 2] + hv.w * wv[kk + 3];
    }
    red[tid] = sum;
    __syncthreads();
    if (tid < 64)
      out[(m0 + tid) * 8 + s] =
          red[tid * 4] + red[tid * 4 + 1] + red[tid * 4 + 2] + red[tid * 4 + 3] + bout[s];
  }
}

extern "C" void kernel_launch(void* const* d_in, const int* in_sizes, int n_in,
                              void* d_out, int out_size, void* d_ws, size_t ws_size,
                              hipStream_t stream) {
  const float* coords = (const float*)d_in[0];
  const float* W0     = (const float*)d_in[1];
  const float* b0     = (const float*)d_in[2];
  const float* Wh     = (const float*)d_in[3];
  const float* bh     = (const float*)d_in[4];
  const float* Wout   = (const float*)d_in[5];
  const float* bout   = (const float*)d_in[6];
  float* out = (float*)d_out;

  const size_t WT_BYTES = (size_t)8 * 4 * 256 * 256 * 2;   // 4 MiB bf16 slabs
  if (ws_size >= WT_BYTES) {
    unsigned short* Wt = (unsigned short*)d_ws;
    convert_wh<<<8192, 256, 0, stream>>>(Wh, Wt);
    // 1563 m-blocks x 128 rows x 8 series; 1562*128+64 = 200000 (tail tile1 dead)
    series_mlp<<<dim3(12504), dim3(256), 0, stream>>>(
        coords, W0, b0, bh, Wout, bout, Wt, out);
  } else {
    series_mlp_slow<<<dim3(3125, 8), dim3(256), 0, stream>>>(
        coords, W0, b0, Wh, bh, Wout, bout, out);
  }
  // second tuple output: echo coords
  hipMemcpyAsync(out + (size_t)200000 * 8, coords,
                 (size_t)200000 * 3 * sizeof(float),
                 hipMemcpyDeviceToDevice, stream);
}

// Round 8
// 928.773 us; speedup vs baseline: 1.1194x; 1.1194x over previous
//
#include <hip/hip_runtime.h>
#include <hip/hip_bf16.h>
#include <cstdint>

typedef __attribute__((ext_vector_type(8))) short short8;
typedef __attribute__((ext_vector_type(4))) float float4v;
typedef __attribute__((ext_vector_type(2))) unsigned int uint2v;

#define LOG2E 1.44269504088896340736f
#define LN2   0.69314718055994530942f

#if __has_builtin(__builtin_amdgcn_exp2f)
__device__ __forceinline__ float fexp2(float x){ return __builtin_amdgcn_exp2f(x); }
#else
__device__ __forceinline__ float fexp2(float x){ return exp2f(x); }
#endif
#if __has_builtin(__builtin_amdgcn_logf)
__device__ __forceinline__ float flog2(float x){ return __builtin_amdgcn_logf(x); }
#else
__device__ __forceinline__ float flog2(float x){ return log2f(x); }
#endif

// hhat = log2(1 + 2^zhat); biases pre-scaled by log2e so GEMM on hhat yields
// the next zhat directly (ln2 * log2e == 1 cancels).
__device__ __forceinline__ float softplus_hat(float zh){
  return flog2(1.0f + fexp2(zh));
}

// softplus output > 0 -> truncation (RTZ) to bf16 is a 1-instr shift.
__device__ __forceinline__ unsigned short bf16_trunc(float f){
  return (unsigned short)(__builtin_bit_cast(unsigned int, f) >> 16);
}

// pack two positive floats into a bf16 pair (lo in low half): one v_perm_b32.
__device__ __forceinline__ unsigned int bf16_pack2(float lo, float hi){
  return __builtin_amdgcn_perm(__builtin_bit_cast(unsigned int, hi),
                               __builtin_bit_cast(unsigned int, lo),
                               0x07060302u);
}

// h tile layout (per 64-row tile): addr(m,c) = m*264 + (m>>2)*16 + c elems.
// (champion layout: 528 B row stride keeps ds_read_b128 aligned; +16-elem
// skew per 4 rows keeps A-reads and packed b64 C-writes at the wave64
// 2-lanes/bank minimum — b64 write bank bases {0,4,..,28} x2 lanes, spans
// disjoint 8-dword runs per lr.)
#define HSTRIDE 264
#define MISTEP  4288                    // 16*264 + 4*16
#define HSIZE   (64 * 264 + 16 * 16)    // 17152 elems = 34304 B per tile

// ---------------------------------------------------------------------------
// Pre-pass: Wh [S,4,256,256] fp32 -> bf16 slabs Wt[s*4+l][kb][n][ki]
// (kb = k/32, ki = k%32). W-frags read from GLOBAL: lanes {n,n+16,n+32,n+48}
// cover row n's 64B contiguously -> 1KB/wave-instr from L2.
// ---------------------------------------------------------------------------
__global__ void convert_wh(const float* __restrict__ Wh,
                           unsigned short* __restrict__ Wt){
  int e = blockIdx.x * 256 + threadIdx.x;          // 0 .. 2^21-1
  int n  = e & 255;
  int k  = (e >> 8) & 255;
  int sl = e >> 16;
  float v = Wh[e];
  __hip_bfloat16 h = __float2bfloat16(v);
  Wt[(sl << 16) + ((k >> 5) << 13) + (n << 5) + (k & 31)] =
      __builtin_bit_cast(unsigned short, h);
}

// OPERAND SWAP (validated R1): A = W-frag, B = h-frag. A/B lane maps are
// symmetric (row/col = lane&15, k-octet = lane>>4) so all reads are
// bit-identical to the champion; only the D mapping flips: per lane,
// D row n = (lane>>4)*4 + reg (+16*ni), D col m = lane&15 (+16*mi).
// -> h-writeback = 4 CONSECUTIVE n at fixed m = one packed ds_write_b64.
__device__ __forceinline__ float4v bf16_mfma(short8 a, short8 b, float4v c){
  return __builtin_amdgcn_mfma_f32_16x16x32_bf16(a, b, c, 0, 0, 0);
}

// layer-0 (K=3) for rows 4j..4j+3 of one 64-row tile, column c
__device__ __forceinline__ void l0_rows(
    unsigned short* __restrict__ ht, const float4v* __restrict__ c4,
    int j, int c, float w0, float w1, float w2, float bb)
{
  float4v x0 = c4[j*3+0], x1 = c4[j*3+1], x2 = c4[j*3+2];
  float z0 = fmaf(x0.z, w2, fmaf(x0.y, w1, fmaf(x0.x, w0, bb)));
  float z1 = fmaf(x1.y, w2, fmaf(x1.x, w1, fmaf(x0.w, w0, bb)));
  float z2 = fmaf(x2.x, w2, fmaf(x1.w, w1, fmaf(x1.z, w0, bb)));
  float z3 = fmaf(x2.w, w2, fmaf(x2.z, w1, fmaf(x2.y, w0, bb)));
  ht[(4*j+0)*HSTRIDE + j*16 + c] = bf16_trunc(softplus_hat(z0));
  ht[(4*j+1)*HSTRIDE + j*16 + c] = bf16_trunc(softplus_hat(z1));
  ht[(4*j+2)*HSTRIDE + j*16 + c] = bf16_trunc(softplus_hat(z2));
  ht[(4*j+3)*HSTRIDE + j*16 + c] = bf16_trunc(softplus_hat(z3));
}

// softplus 2 els of the OTHER tile's acc; on odd subs emit one packed b64
// (4 consecutive n at fixed m). Frag idx = 2kb + (sub>>1); compile-time.
__device__ __forceinline__ void spw2(const float4v (&acc)[4][4],
    unsigned short* __restrict__ cw, unsigned int& uh, int kb, int sub)
{
  const int idx = kb * 2 + (sub >> 1);
  const int mi = idx >> 2, ni = idx & 3;
  float4v v = acc[mi][ni];
  if (!(sub & 1)) {
    uh = bf16_pack2(softplus_hat(v.x), softplus_hat(v.y));
  } else {
    uint2v dd;
    dd.x = uh;
    dd.y = bf16_pack2(softplus_hat(v.z), softplus_hat(v.w));
    *(uint2v*)(cw + mi * MISTEP + ni * 16) = dd;
  }
}

// softplus + output-dot of 2 els (last layer): p[mi] over this lane's m-col.
__device__ __forceinline__ void spdot2(const float4v (&acc)[4][4],
    const float4v (&wv4)[4], float (&p)[4], int kb, int sub)
{
  const int idx = kb * 2 + (sub >> 1);
  const int mi = idx >> 2, ni = idx & 3;
  const int r0 = (sub & 1) * 2;
  float4v v = acc[mi][ni];
  #pragma unroll
  for (int r = r0; r < r0 + 2; ++r)
    p[mi] = fmaf(softplus_hat(v[r]), wv4[ni][r], p[mi]);
}

// ---------------------------------------------------------------------------
// One phase = champion K-loop (16 mfma/kb, A depth-1 LDS prefetch, rotating
// depth-3 W prefetch, slot=(8*PH+kb)%3 continuous; kb 5..7 prefetch the NEXT
// phase's kb 0..2 from bn), 4 substeps/kb with sched_barrier(0) pins and the
// other tile's VALU chunk interleaved per substep.
// ---------------------------------------------------------------------------
template<int PH, bool LOADN, class F>
__device__ __forceinline__ void mfma_phase(
    const unsigned short* __restrict__ bb,   // this phase's slab + lane offset
    const unsigned short* __restrict__ bn,   // next phase's slab + lane offset
    const unsigned short* __restrict__ aptr, // h tile + lane h-frag base
    short8 (&bq)[3][4], float4v (&acc)[4][4], F&& other)
{
  short8 a0[4], a1[4];
  #pragma unroll
  for (int mi = 0; mi < 4; ++mi)
    a0[mi] = *(const short8*)(aptr + mi * MISTEP);

  #pragma unroll
  for (int kb = 0; kb < 8; ++kb) {
    short8* cur = (kb & 1) ? a1 : a0;
    short8* nxt = (kb & 1) ? a0 : a1;
    const int slot = (8 * PH + kb) % 3;            // compile-time (unrolled)
    #pragma unroll
    for (int sub = 0; sub < 4; ++sub) {
      // ---- MFMA group: h-frag cur[sub] (B) x 4 W-frags (A) ----
      #pragma unroll
      for (int ni = 0; ni < 4; ++ni)
        acc[sub][ni] = bf16_mfma(bq[slot][ni], cur[sub], acc[sub][ni]);
      // ---- memory-issue slots (champion depths) ----
      if (sub == 1 && kb < 7) {                    // h prefetch depth 1 (LDS)
        #pragma unroll
        for (int mi = 0; mi < 4; ++mi)
          nxt[mi] = *(const short8*)(aptr + (kb + 1) * 32 + mi * MISTEP);
      }
      if (sub == 3) {
        if (kb < 5) {                              // W depth-3, this phase
          #pragma unroll
          for (int ni = 0; ni < 4; ++ni)
            bq[slot][ni] = *(const short8*)(bb + (kb + 3) * 8192 + ni * 512);
        } else if (LOADN) {                        // next phase's kb 0..2
          #pragma unroll
          for (int ni = 0; ni < 4; ++ni)
            bq[slot][ni] = *(const short8*)(bn + (kb - 5) * 8192 + ni * 512);
        }
      }
      __builtin_amdgcn_sched_barrier(0);
      other(kb, sub);                              // ~2 softplus els (VALU)
      __builtin_amdgcn_sched_barrier(0);
    }
  }
}

// ---------------------------------------------------------------------------
// Fused MLP: one workgroup owns TWO 64-row tiles (128 rows) in anti-phase.
// Each phase: K-loop(tile X, layer l) with tile Y's softplus interleaved.
// 4 waves, wave tile 64m x 64n, one series/block, s = blk&7.
// LDS: 2 h tiles + cbuf + bias stage = 74.2 KB -> 2 blocks/CU.
// ---------------------------------------------------------------------------
__global__ __launch_bounds__(256, 2) void series_mlp(
    const float* __restrict__ coords,
    const float* __restrict__ W0, const float* __restrict__ b0,
    const float* __restrict__ bh,
    const float* __restrict__ Wout, const float* __restrict__ bout,
    const unsigned short* __restrict__ Wt,
    float* __restrict__ out)
{
  __shared__ __align__(16) unsigned short h_lds[2 * HSIZE];   // 68608 B
  __shared__ float cbuf[384];
  __shared__ __align__(16) float bias_lds[1024];              // 4 KB

  const int tid  = threadIdx.x;
  const int lane = tid & 63;
  const int wave = tid >> 6;
  const int s    = blockIdx.x & 7;           // series == XCD
  const int m0   = (blockIdx.x >> 3) * 128;  // 1563 m-blocks; tail tile1 dead

  const int q    = lane >> 4;
  const int lr   = lane & 15;
  const int colb = (wave << 6) + lr;

  // coords for 128 rows (tail block: clamp index -> finite garbage, unwritten)
  {
    int i1 = m0 * 3 + tid;
    int i2 = i1 + 256;
    cbuf[tid] = coords[i1 < 599999 ? i1 : 599999];
    if (tid < 128) cbuf[tid + 256] = coords[i2 < 599999 ? i2 : 599999];
  }
  // stage pre-scaled biases (L2-resident; read per phase as float4)
  {
    const float* bh_s = bh + (s << 10);
    #pragma unroll
    for (int l = 0; l < 4; ++l)
      bias_lds[l * 256 + tid] = bh_s[l * 256 + tid] * LOG2E;
  }

  // layer-0 weights for this thread's column (shared by both tiles)
  const int c = tid;
  const float w0  = W0[(s * 3 + 0) * 256 + c] * LOG2E;
  const float w1  = W0[(s * 3 + 1) * 256 + c] * LOG2E;
  const float w2  = W0[(s * 3 + 2) * 256 + c] * LOG2E;
  const float bb0 = b0[s * 256 + c] * LOG2E;

  // W-frag lane base (A-operand after swap; addressing identical to champion)
  const unsigned short* bbase0 = Wt + ((s << 2) << 16) + (colb << 5) + (q << 3);
  short8 bq[3][4];
  #pragma unroll
  for (int i = 0; i < 3; ++i)
    #pragma unroll
    for (int ni = 0; ni < 4; ++ni)
      bq[i][ni] = *(const short8*)(bbase0 + i * 8192 + ni * 512);

  // Wout for this lane's n-range (hoisted; 4 float4)
  float4v wv4[4];
  #pragma unroll
  for (int ni = 0; ni < 4; ++ni)
    wv4[ni] = *(const float4v*)(Wout + (s << 8) + (wave << 6) + ni * 16 +
                                (q << 2));

  // h-frag lane base (B-operand; identical addressing to champion A-frags)
  const unsigned short* aptrA = h_lds + lr * HSTRIDE + (lr >> 2) * 16 + (q << 3);
  const unsigned short* aptrB = aptrA + HSIZE;
  // packed C-write lane base: m = lr (+16mi), n = wave*64 + ni*16 + q*4 (+r)
  unsigned short* cwA = h_lds + lr * HSTRIDE + (lr >> 2) * 16 + (wave << 6) +
                        (q << 2);
  unsigned short* cwB = cwA + HSIZE;

  const float4v* c4 = (const float4v*)cbuf;

  __syncthreads();                      // cbuf + bias stage ready
  #pragma unroll
  for (int j = 0; j < 16; ++j)          // layer 0, tile A (exposed prologue)
    l0_rows(h_lds, c4, j, c, w0, w1, w2, bb0);
  __syncthreads();                      // hA(0) ready

  float4v accA[4][4], accB[4][4];

  // bias init: D rows n = wave*64 + ni*16 + q*4 + r -> one float4 per ni.
#define INIT_ACC(ACC, LIDX)                                                   \
  {                                                                           \
    float4v b4[4];                                                            \
    _Pragma("unroll")                                                         \
    for (int ni = 0; ni < 4; ++ni)                                            \
      b4[ni] = *(const float4v*)&bias_lds[(LIDX) * 256 + (wave << 6) +        \
                                          ni * 16 + (q << 2)];                \
    _Pragma("unroll")                                                         \
    for (int mi = 0; mi < 4; ++mi)                                            \
      _Pragma("unroll")                                                       \
      for (int ni = 0; ni < 4; ++ni)                                          \
        ACC[mi][ni] = b4[ni];                                                 \
  }

  const unsigned short* B0 = bbase0;
  const unsigned short* B1 = bbase0 + 65536;
  const unsigned short* B2 = bbase0 + 2 * 65536;
  const unsigned short* B3 = bbase0 + 3 * 65536;

  // P0: K(tA, l0) || layer-0 for tile B (one row-quad on subs 0 and 2)
  INIT_ACC(accA, 0)
  mfma_phase<0, true>(B0, B0, aptrA, bq, accA, [&](int kb, int sub){
    if (sub == 0) l0_rows(h_lds + HSIZE, c4 + 48, 2 * kb + 0, c, w0, w1, w2, bb0);
    if (sub == 2) l0_rows(h_lds + HSIZE, c4 + 48, 2 * kb + 1, c, w0, w1, w2, bb0);
  });
  __syncthreads();                      // hB(0) ready

  unsigned int uh;                      // pack state for spw2

  // P1: K(tB, l0) || softplus(accA) -> hA(1)
  INIT_ACC(accB, 0)
  mfma_phase<1, true>(B0, B1, aptrB, bq, accB,
      [&](int kb, int sub){ spw2(accA, cwA, uh, kb, sub); });
  __syncthreads();                      // hA(1) ready

  // P2: K(tA, l1) || softplus(accB) -> hB(1)
  INIT_ACC(accA, 1)
  mfma_phase<2, true>(B1, B1, aptrA, bq, accA,
      [&](int kb, int sub){ spw2(accB, cwB, uh, kb, sub); });
  __syncthreads();                      // hB(1) ready

  // P3: K(tB, l1) || softplus(accA) -> hA(2)
  INIT_ACC(accB, 1)
  mfma_phase<3, true>(B1, B2, aptrB, bq, accB,
      [&](int kb, int sub){ spw2(accA, cwA, uh, kb, sub); });
  __syncthreads();                      // hA(2) ready

  // P4: K(tA, l2) || softplus(accB) -> hB(2)
  INIT_ACC(accA, 2)
  mfma_phase<4, true>(B2, B2, aptrA, bq, accA,
      [&](int kb, int sub){ spw2(accB, cwB, uh, kb, sub); });
  __syncthreads();                      // hB(2) ready

  // P5: K(tB, l2) || softplus(accA) -> hA(3)
  INIT_ACC(accB, 2)
  mfma_phase<5, true>(B2, B3, aptrB, bq, accB,
      [&](int kb, int sub){ spw2(accA, cwA, uh, kb, sub); });
  __syncthreads();                      // hA(3) ready

  // P6: K(tA, l3) || softplus(accB) -> hB(3)
  INIT_ACC(accA, 3)
  mfma_phase<6, true>(B3, B3, aptrA, bq, accA,
      [&](int kb, int sub){ spw2(accB, cwB, uh, kb, sub); });
  __syncthreads();                      // hB(3) ready

  // P7: K(tB, l3) || softplus+output-dot of accA
  INIT_ACC(accB, 3)
  float pA[4] = {0.f, 0.f, 0.f, 0.f};
  float pB[4] = {0.f, 0.f, 0.f, 0.f};
  mfma_phase<7, false>(B3, B3, aptrB, bq, accB,
      [&](int kb, int sub){ spdot2(accA, wv4, pA, kb, sub); });

  #pragma unroll
  for (int kb = 0; kb < 8; ++kb)        // tile B's dot (exposed epilogue)
    #pragma unroll
    for (int sub = 0; sub < 4; ++sub)
      spdot2(accB, wv4, pB, kb, sub);

  // reduce across q-groups: lanes {lr, lr+16, lr+32, lr+48} hold the wave's
  // 4 n-slices of row m = lr + 16*mi.
  #pragma unroll
  for (int mi = 0; mi < 4; ++mi) {
    pA[mi] += __shfl_xor(pA[mi], 16); pA[mi] += __shfl_xor(pA[mi], 32);
    pB[mi] += __shfl_xor(pB[mi], 16); pB[mi] += __shfl_xor(pB[mi], 32);
  }

  // cross-wave reduce: red[tile][m][wave], 512 floats in hA's region.
  __syncthreads();                      // all P7 h-reads of hB done
  float* redA = (float*)h_lds;
  float* redB = redA + 256;
  if (lane < 16) {
    #pragma unroll
    for (int mi = 0; mi < 4; ++mi) {
      redA[(mi * 16 + lr) * 4 + wave] = pA[mi];
      redB[(mi * 16 + lr) * 4 + wave] = pB[mi];
    }
  }
  __syncthreads();

  if (tid < 128) {
    const int t = tid & 63;
    const float* red = (tid < 64) ? redA : redB;
    float4v r4 = ((const float4v*)red)[t];
    float tot = (r4.x + r4.y) + (r4.z + r4.w);
    int row = m0 + ((tid >> 6) << 6) + t;
    if (row < 200000)
      out[row * 8 + s] = fmaf(LN2, tot, bout[s]);  // undo log2-domain
  }
#undef INIT_ACC
}

// ---------------------------------------------------------------------------
// Fallback (scratch-free), fp32 VALU — only if ws_size < 4 MiB.
// ---------------------------------------------------------------------------
__global__ __launch_bounds__(256) void series_mlp_slow(
    const float* __restrict__ coords,
    const float* __restrict__ W0, const float* __restrict__ b0,
    const float* __restrict__ Wh, const float* __restrict__ bh,
    const float* __restrict__ Wout, const float* __restrict__ bout,
    float* __restrict__ out)
{
  __shared__ float hh[64 * 256];
  __shared__ float cbuf[192];
  __shared__ float red[256];
  const int tid = threadIdx.x;
  const int s   = blockIdx.y;
  const int m0  = blockIdx.x * 64;

  if (tid < 192) cbuf[tid] = coords[m0 * 3 + tid];
  __syncthreads();
  {
    const float w0 = W0[(s * 3 + 0) * 256 + tid];
    const float w1 = W0[(s * 3 + 1) * 256 + tid];
    const float w2 = W0[(s * 3 + 2) * 256 + tid];
    const float bb = b0[s * 256 + tid];
    for (int m = 0; m < 64; ++m) {
      float z = fmaf(cbuf[m * 3 + 2], w2,
                fmaf(cbuf[m * 3 + 1], w1,
                fmaf(cbuf[m * 3 + 0], w0, bb)));
      hh[m * 256 + tid] = LN2 * softplus_hat(z * LOG2E);
    }
  }
  __syncthreads();

  for (int l = 0; l < 4; ++l) {
    const float* W = Wh + (((s << 2) + l) << 16);
    const float bb = bh[((s << 2) + l) * 256 + tid];
    float acc[64];
    #pragma unroll
    for (int m = 0; m < 64; ++m) acc[m] = bb;
    for (int kc = 0; kc < 64; ++kc) {
      float w0 = W[(kc * 4 + 0) * 256 + tid];
      float w1 = W[(kc * 4 + 1) * 256 + tid];
      float w2 = W[(kc * 4 + 2) * 256 + tid];
      float w3 = W[(kc * 4 + 3) * 256 + tid];
      #pragma unroll
      for (int m = 0; m < 64; ++m) {
        float4v hv = *(const float4v*)&hh[m * 256 + kc * 4];
        acc[m] = fmaf(hv.w, w3, fmaf(hv.z, w2,
                 fmaf(hv.y, w1, fmaf(hv.x, w0, acc[m]))));
      }
    }
    __syncthreads();
    #pragma unroll
    for (int m = 0; m < 64; ++m)
      hh[m * 256 + tid] = LN2 * softplus_hat(acc[m] * LOG2E);
    __syncthreads();
  }
  {
    const int m = tid >> 2, qq = tid & 3;
    const float* wv = Wout + (s << 8);
    float sum = 0.f;
    for (int i = 0; i < 16; ++i) {
      int kk = (qq << 6) + ((((tid & 15) + i) << 2) & 63);
      float4v hv = *(const float4v*)&hh[m * 256 + kk];
      sum += hv.x * wv[kk] + hv.y * wv[kk + 1] + hv.z * wv[kk + 2] + hv.w * wv[kk + 3];
    }
    red[tid] = sum;
    __syncthreads();
    if (tid < 64)
      out[(m0 + tid) * 8 + s] =
          red[tid * 4] + red[tid * 4 + 1] + red[tid * 4 + 2] + red[tid * 4 + 3] + bout[s];
  }
}

extern "C" void kernel_launch(void* const* d_in, const int* in_sizes, int n_in,
                              void* d_out, int out_size, void* d_ws, size_t ws_size,
                              hipStream_t stream) {
  const float* coords = (const float*)d_in[0];
  const float* W0     = (const float*)d_in[1];
  const float* b0     = (const float*)d_in[2];
  const float* Wh     = (const float*)d_in[3];
  const float* bh     = (const float*)d_in[4];
  const float* Wout   = (const float*)d_in[5];
  const float* bout   = (const float*)d_in[6];
  float* out = (float*)d_out;

  const size_t WT_BYTES = (size_t)8 * 4 * 256 * 256 * 2;   // 4 MiB bf16 slabs
  if (ws_size >= WT_BYTES) {
    unsigned short* Wt = (unsigned short*)d_ws;
    convert_wh<<<8192, 256, 0, stream>>>(Wh, Wt);
    // 1563 m-blocks x 128 rows x 8 series; 1562*128+64 = 200000 (tail tile1 dead)
    series_mlp<<<dim3(12504), dim3(256), 0, stream>>>(
        coords, W0, b0, bh, Wout, bout, Wt, out);
  } else {
    series_mlp_slow<<<dim3(3125, 8), dim3(256), 0, stream>>>(
        coords, W0, b0, Wh, bh, Wout, bout, out);
  }
  // second tuple output: echo coords
  hipMemcpyAsync(out + (size_t)200000 * 8, coords,
                 (size_t)200000 * 3 * sizeof(float),
                 hipMemcpyDeviceToDevice, stream);
}

// Round 9
// 887.565 us; speedup vs baseline: 1.1713x; 1.0464x over previous
//
#include <hip/hip_runtime.h>
#include <hip/hip_bf16.h>
#include <cstdint>

typedef __attribute__((ext_vector_type(8))) short short8;
typedef __attribute__((ext_vector_type(4))) float float4v;

#define LOG2E 1.44269504088896340736f
#define LN2   0.69314718055994530942f

#if __has_builtin(__builtin_amdgcn_exp2f)
__device__ __forceinline__ float fexp2(float x){ return __builtin_amdgcn_exp2f(x); }
#else
__device__ __forceinline__ float fexp2(float x){ return exp2f(x); }
#endif
#if __has_builtin(__builtin_amdgcn_logf)
__device__ __forceinline__ float flog2(float x){ return __builtin_amdgcn_logf(x); }
#else
__device__ __forceinline__ float flog2(float x){ return log2f(x); }
#endif

// hhat = log2(1 + 2^zhat); biases pre-scaled by log2e so GEMM on hhat yields
// the next zhat directly (ln2 * log2e == 1 cancels).
__device__ __forceinline__ float softplus_hat(float zh){
  return flog2(1.0f + fexp2(zh));
}

// softplus output > 0 -> truncation (RTZ) to bf16 is a 1-instr shift.
__device__ __forceinline__ unsigned short bf16_trunc(float f){
  return (unsigned short)(__builtin_bit_cast(unsigned int, f) >> 16);
}

// h tile layout (per 64-row tile): addr(m,c) = m*264 + (m>>2)*16 + c elems.
// (champion layout: 528 B row stride keeps ds_read_b128 aligned; +16-elem
// skew per 4 rows keeps A-reads and scalar b16 C-writes at the wave64
// 2-lanes/bank minimum. R8 measured: packed-b64 variants INCREASE conflicts.)
#define HSTRIDE 264
#define MISTEP  4288                    // 16*264 + 4*16
#define HSIZE   (64 * 264 + 16 * 16)    // 17152 elems = 34304 B per tile

// ---------------------------------------------------------------------------
// Pre-pass: Wh [S,4,256,256] fp32 -> bf16 slabs Wt[s*4+l][kb][n][ki]
// (kb = k/32, ki = k%32). B-frags read from GLOBAL: lanes {n,n+16,n+32,n+48}
// cover row n's 64B contiguously -> 1KB/wave-instr from L2.
// ---------------------------------------------------------------------------
__global__ void convert_wh(const float* __restrict__ Wh,
                           unsigned short* __restrict__ Wt){
  int e = blockIdx.x * 256 + threadIdx.x;          // 0 .. 2^21-1
  int n  = e & 255;
  int k  = (e >> 8) & 255;
  int sl = e >> 16;
  float v = Wh[e];
  __hip_bfloat16 h = __float2bfloat16(v);
  Wt[(sl << 16) + ((k >> 5) << 13) + (n << 5) + (k & 31)] =
      __builtin_bit_cast(unsigned short, h);
}

__device__ __forceinline__ float4v bf16_mfma(short8 a, short8 b, float4v c){
  return __builtin_amdgcn_mfma_f32_16x16x32_bf16(a, b, c, 0, 0, 0);
}

// layer-0 (K=3) for rows 4j..4j+3 of one 64-row tile, column c
__device__ __forceinline__ void l0_rows(
    unsigned short* __restrict__ ht, const float4v* __restrict__ c4,
    int j, int c, float w0, float w1, float w2, float bb)
{
  float4v x0 = c4[j*3+0], x1 = c4[j*3+1], x2 = c4[j*3+2];
  float z0 = fmaf(x0.z, w2, fmaf(x0.y, w1, fmaf(x0.x, w0, bb)));
  float z1 = fmaf(x1.y, w2, fmaf(x1.x, w1, fmaf(x0.w, w0, bb)));
  float z2 = fmaf(x2.x, w2, fmaf(x1.w, w1, fmaf(x1.z, w0, bb)));
  float z3 = fmaf(x2.w, w2, fmaf(x2.z, w1, fmaf(x2.y, w0, bb)));
  ht[(4*j+0)*HSTRIDE + j*16 + c] = bf16_trunc(softplus_hat(z0));
  ht[(4*j+1)*HSTRIDE + j*16 + c] = bf16_trunc(softplus_hat(z1));
  ht[(4*j+2)*HSTRIDE + j*16 + c] = bf16_trunc(softplus_hat(z2));
  ht[(4*j+3)*HSTRIDE + j*16 + c] = bf16_trunc(softplus_hat(z3));
}

// softplus + write-back of 2 ELEMENTS (substep granularity) of the OTHER
// tile's acc. Frag idx = 2*kb + (sub>>1), elements r0..r0+1, r0 = (sub&1)*2.
// kb,sub compile-time after unrolling -> pure base+immediate LDS stores.
__device__ __forceinline__ void sp2s(const float4v (&acc)[4][4],
    unsigned short* __restrict__ cptr, int kb, int sub)
{
  const int idx = kb * 2 + (sub >> 1);
  const int mi = idx >> 2, ni = idx & 3;
  const int r0 = (sub & 1) * 2;
  float4v v = acc[mi][ni];
  #pragma unroll
  for (int r = r0; r < r0 + 2; ++r)
    cptr[mi * MISTEP + r * HSTRIDE + ni * 16] = bf16_trunc(softplus_hat(v[r]));
}

// softplus + output-dot of 2 elements of the OTHER tile's acc (last layer)
__device__ __forceinline__ void spdot2s(const float4v (&acc)[4][4],
    const float (&wv)[4], float (&p)[16], int kb, int sub)
{
  const int idx = kb * 2 + (sub >> 1);
  const int mi = idx >> 2, ni = idx & 3;
  const int r0 = (sub & 1) * 2;
  float4v v = acc[mi][ni];
  #pragma unroll
  for (int r = r0; r < r0 + 2; ++r)
    p[mi * 4 + r] = fmaf(softplus_hat(v[r]), wv[ni], p[mi * 4 + r]);
}

// ---------------------------------------------------------------------------
// One phase = champion K-loop split into 4 SUBSTEPS per kb, with
// sched_barrier(0) pins: {4 MFMA + mem-issue slot} / {~2 softplus elems}
// alternation. Memory issue distance preserved (A-prefetch sub 1 -> used
// next kb; B depth-3 global prefetch sub 3 -> used 3 kbs later).
// ---------------------------------------------------------------------------
template<int PH, bool LOADN, class F>
__device__ __forceinline__ void mfma_phase(
    const unsigned short* __restrict__ bb,   // this phase's slab + lane offset
    const unsigned short* __restrict__ bn,   // next phase's slab + lane offset
    const unsigned short* __restrict__ aptr, // h tile + lane A-base
    short8 (&bq)[3][4], float4v (&acc)[4][4], F&& other)
{
  short8 a0[4], a1[4];
  #pragma unroll
  for (int mi = 0; mi < 4; ++mi)
    a0[mi] = *(const short8*)(aptr + mi * MISTEP);

  #pragma unroll
  for (int kb = 0; kb < 8; ++kb) {
    short8* cur = (kb & 1) ? a1 : a0;
    short8* nxt = (kb & 1) ? a0 : a1;
    const int slot = (8 * PH + kb) % 3;            // compile-time (unrolled)
    #pragma unroll
    for (int sub = 0; sub < 4; ++sub) {
      // ---- MFMA group: A-frag cur[sub] x 4 B-frags ----
      #pragma unroll
      for (int ni = 0; ni < 4; ++ni)
        acc[sub][ni] = bf16_mfma(cur[sub], bq[slot][ni], acc[sub][ni]);
      // ---- memory-issue slots ----
      if (sub == 1 && kb < 7) {                    // A prefetch depth 1 (LDS)
        #pragma unroll
        for (int mi = 0; mi < 4; ++mi)
          nxt[mi] = *(const short8*)(aptr + (kb + 1) * 32 + mi * MISTEP);
      }
      if (sub == 3) {
        if (kb < 5) {                              // B depth-3, this phase
          #pragma unroll
          for (int ni = 0; ni < 4; ++ni)
            bq[slot][ni] = *(const short8*)(bb + (kb + 3) * 8192 + ni * 512);
        } else if (LOADN) {                        // next phase's kb 0..2
          #pragma unroll
          for (int ni = 0; ni < 4; ++ni)
            bq[slot][ni] = *(const short8*)(bn + (kb - 5) * 8192 + ni * 512);
        }
      }
      __builtin_amdgcn_sched_barrier(0);
      other(kb, sub);                              // ~2 softplus elems (VALU)
      __builtin_amdgcn_sched_barrier(0);
    }
  }
}

// ---------------------------------------------------------------------------
// Fused MLP: one workgroup owns TWO 64-row tiles (128 rows) in anti-phase.
// Each phase: K-loop(tile X, layer l) with tile Y's softplus interleaved
// at substep granularity. 4 waves, wave tile 64m x 64n, one series/block,
// s = blk&7. LDS: 2 x 34304 B tiles + cbuf = 70 KB -> 2 blocks/CU.
// All bh biases and Wout hoisted to prologue registers (loads hide under
// layer-0); phases carry no VMEM scalar traffic besides the B slabs.
// TERMINAL: wall = matrix(41%) + VALU(50%) + ~9% barrier residual; pipes
// measured issue-additive per SIMD across 7 structural variants.
// ---------------------------------------------------------------------------
__global__ __launch_bounds__(256, 2) void series_mlp(
    const float* __restrict__ coords,
    const float* __restrict__ W0, const float* __restrict__ b0,
    const float* __restrict__ bh,
    const float* __restrict__ Wout, const float* __restrict__ bout,
    const unsigned short* __restrict__ Wt,
    float* __restrict__ out)
{
  __shared__ __align__(16) unsigned short h_lds[2 * HSIZE];   // 68608 B
  __shared__ float cbuf[384];

  const int tid  = threadIdx.x;
  const int lane = tid & 63;
  const int wave = tid >> 6;
  const int s    = blockIdx.x & 7;           // series == XCD
  const int m0   = (blockIdx.x >> 3) * 128;  // 1563 m-blocks; tail tile1 dead

  const int q    = lane >> 4;
  const int lr   = lane & 15;
  const int colb = (wave << 6) + lr;

  // coords for 128 rows (tail block: clamp index -> finite garbage, unwritten)
  {
    int i1 = m0 * 3 + tid;
    int i2 = i1 + 256;
    cbuf[tid] = coords[i1 < 599999 ? i1 : 599999];
    if (tid < 128) cbuf[tid + 256] = coords[i2 < 599999 ? i2 : 599999];
  }

  // layer-0 weights for this thread's column (shared by both tiles)
  const int c = tid;
  const float w0  = W0[(s * 3 + 0) * 256 + c] * LOG2E;
  const float w1  = W0[(s * 3 + 1) * 256 + c] * LOG2E;
  const float w2  = W0[(s * 3 + 2) * 256 + c] * LOG2E;
  const float bb0 = b0[s * 256 + c] * LOG2E;

  // B-frag lane base + initial 3-slot fill (issued early: hides L2 latency
  // under the layer-0 VALU work)
  const unsigned short* bbase0 = Wt + ((s << 2) << 16) + (colb << 5) + (q << 3);
  short8 bq[3][4];
  #pragma unroll
  for (int i = 0; i < 3; ++i)
    #pragma unroll
    for (int ni = 0; ni < 4; ++ni)
      bq[i][ni] = *(const short8*)(bbase0 + i * 8192 + ni * 512);

  // bias/Wout preload (hoisted out of the phase stream; L2-resident)
  const float* bh_s = bh + (s << 10);
  float bias_r[4][4];
  #pragma unroll
  for (int l = 0; l < 4; ++l)
    #pragma unroll
    for (int ni = 0; ni < 4; ++ni)
      bias_r[l][ni] = bh_s[l * 256 + colb + ni * 16] * LOG2E;
  float wv[4];
  #pragma unroll
  for (int ni = 0; ni < 4; ++ni)
    wv[ni] = Wout[(s << 8) + colb + ni * 16];

  // A-frag / C-write lane bases per tile (champion addressing, verbatim)
  const unsigned short* aptrA = h_lds + lr * HSTRIDE + (lr >> 2) * 16 + (q << 3);
  const unsigned short* aptrB = aptrA + HSIZE;
  unsigned short* cptrA = h_lds + q * 1072 + colb;
  unsigned short* cptrB = cptrA + HSIZE;

  const float4v* c4 = (const float4v*)cbuf;

  __syncthreads();                      // cbuf ready
  #pragma unroll
  for (int j = 0; j < 16; ++j)          // layer 0, tile A (exposed prologue)
    l0_rows(h_lds, c4, j, c, w0, w1, w2, bb0);
  __syncthreads();                      // hA(0) ready

  float4v accA[4][4], accB[4][4];

#define INIT_ACC(ACC, LIDX)                                                   \
  {                                                                           \
    _Pragma("unroll")                                                         \
    for (int mi = 0; mi < 4; ++mi)                                            \
      _Pragma("unroll")                                                       \
      for (int ni = 0; ni < 4; ++ni)                                          \
        ACC[mi][ni] = (float4v){bias_r[LIDX][ni], bias_r[LIDX][ni],           \
                                bias_r[LIDX][ni], bias_r[LIDX][ni]};          \
  }

  const unsigned short* B0 = bbase0;
  const unsigned short* B1 = bbase0 + 65536;
  const unsigned short* B2 = bbase0 + 2 * 65536;
  const unsigned short* B3 = bbase0 + 3 * 65536;

  // P0: K(tA, l0) || layer-0 for tile B (one row-quad on subs 0 and 2)
  INIT_ACC(accA, 0)
  mfma_phase<0, true>(B0, B0, aptrA, bq, accA, [&](int kb, int sub){
    if (sub == 0) l0_rows(h_lds + HSIZE, c4 + 48, 2 * kb + 0, c, w0, w1, w2, bb0);
    if (sub == 2) l0_rows(h_lds + HSIZE, c4 + 48, 2 * kb + 1, c, w0, w1, w2, bb0);
  });
  __syncthreads();                      // hB(0) ready

  // P1: K(tB, l0) || softplus(accA) -> hA(1)
  INIT_ACC(accB, 0)
  mfma_phase<1, true>(B0, B1, aptrB, bq, accB,
      [&](int kb, int sub){ sp2s(accA, cptrA, kb, sub); });
  __syncthreads();                      // hA(1) ready

  // P2: K(tA, l1) || softplus(accB) -> hB(1)
  INIT_ACC(accA, 1)
  mfma_phase<2, true>(B1, B1, aptrA, bq, accA,
      [&](int kb, int sub){ sp2s(accB, cptrB, kb, sub); });
  __syncthreads();                      // hB(1) ready

  // P3: K(tB, l1) || softplus(accA) -> hA(2)
  INIT_ACC(accB, 1)
  mfma_phase<3, true>(B1, B2, aptrB, bq, accB,
      [&](int kb, int sub){ sp2s(accA, cptrA, kb, sub); });
  __syncthreads();                      // hA(2) ready

  // P4: K(tA, l2) || softplus(accB) -> hB(2)
  INIT_ACC(accA, 2)
  mfma_phase<4, true>(B2, B2, aptrA, bq, accA,
      [&](int kb, int sub){ sp2s(accB, cptrB, kb, sub); });
  __syncthreads();                      // hB(2) ready

  // P5: K(tB, l2) || softplus(accA) -> hA(3)
  INIT_ACC(accB, 2)
  mfma_phase<5, true>(B2, B3, aptrB, bq, accB,
      [&](int kb, int sub){ sp2s(accA, cptrA, kb, sub); });
  __syncthreads();                      // hA(3) ready

  // P6: K(tA, l3) || softplus(accB) -> hB(3)
  INIT_ACC(accA, 3)
  mfma_phase<6, true>(B3, B3, aptrA, bq, accA,
      [&](int kb, int sub){ sp2s(accB, cptrB, kb, sub); });
  __syncthreads();                      // hB(3) ready

  // P7: K(tB, l3) || softplus+output-dot of accA
  INIT_ACC(accB, 3)
  float pA[16], pB[16];
  #pragma unroll
  for (int i = 0; i < 16; ++i) pA[i] = 0.f;
  mfma_phase<7, false>(B3, B3, aptrB, bq, accB,
      [&](int kb, int sub){ spdot2s(accA, wv, pA, kb, sub); });

  #pragma unroll
  for (int i = 0; i < 16; ++i) pB[i] = 0.f;
  #pragma unroll
  for (int kb = 0; kb < 8; ++kb)        // tile B's dot (exposed epilogue)
    #pragma unroll
    for (int sub = 0; sub < 4; ++sub)
      spdot2s(accB, wv, pB, kb, sub);

  // cross-wave reduce: 2 regions of 64 rows x 64 partials (stride-68 pad).
  // Barrier first: other waves may still be doing P7 A-reads from hB.
  __syncthreads();
  float* redA = (float*)h_lds;
  float* redB = redA + 64 * 68;
  #pragma unroll
  for (int mi = 0; mi < 4; ++mi)
    #pragma unroll
    for (int r = 0; r < 4; ++r) {
      int row = mi * 16 + (q << 2) + r;
      redA[row * 68 + (wave << 4) + lr] = pA[mi * 4 + r];
      redB[row * 68 + (wave << 4) + lr] = pB[mi * 4 + r];
    }
  __syncthreads();

  if (tid < 128) {
    const int t = tid & 63;
    const float* red = (tid < 64) ? redA : redB;
    const float4v* rr = (const float4v*)&red[t * 68];
    float4v a = rr[0];
    #pragma unroll
    for (int i = 1; i < 16; ++i) {
      float4v b = rr[i];
      a.x += b.x; a.y += b.y; a.z += b.z; a.w += b.w;
    }
    float tot = (a.x + a.y) + (a.z + a.w);
    int row = m0 + ((tid >> 6) << 6) + t;
    if (row < 200000)
      out[row * 8 + s] = fmaf(LN2, tot, bout[s]);  // undo log2-domain
  }
#undef INIT_ACC
}

// ---------------------------------------------------------------------------
// Fallback (scratch-free), fp32 VALU — only if ws_size < 4 MiB.
// ---------------------------------------------------------------------------
__global__ __launch_bounds__(256) void series_mlp_slow(
    const float* __restrict__ coords,
    const float* __restrict__ W0, const float* __restrict__ b0,
    const float* __restrict__ Wh, const float* __restrict__ bh,
    const float* __restrict__ Wout, const float* __restrict__ bout,
    float* __restrict__ out)
{
  __shared__ float hh[64 * 256];
  __shared__ float cbuf[192];
  __shared__ float red[256];
  const int tid = threadIdx.x;
  const int s   = blockIdx.y;
  const int m0  = blockIdx.x * 64;

  if (tid < 192) cbuf[tid] = coords[m0 * 3 + tid];
  __syncthreads();
  {
    const float w0 = W0[(s * 3 + 0) * 256 + tid];
    const float w1 = W0[(s * 3 + 1) * 256 + tid];
    const float w2 = W0[(s * 3 + 2) * 256 + tid];
    const float bb = b0[s * 256 + tid];
    for (int m = 0; m < 64; ++m) {
      float z = fmaf(cbuf[m * 3 + 2], w2,
                fmaf(cbuf[m * 3 + 1], w1,
                fmaf(cbuf[m * 3 + 0], w0, bb)));
      hh[m * 256 + tid] = LN2 * softplus_hat(z * LOG2E);
    }
  }
  __syncthreads();

  for (int l = 0; l < 4; ++l) {
    const float* W = Wh + (((s << 2) + l) << 16);
    const float bb = bh[((s << 2) + l) * 256 + tid];
    float acc[64];
    #pragma unroll
    for (int m = 0; m < 64; ++m) acc[m] = bb;
    for (int kc = 0; kc < 64; ++kc) {
      float w0 = W[(kc * 4 + 0) * 256 + tid];
      float w1 = W[(kc * 4 + 1) * 256 + tid];
      float w2 = W[(kc * 4 + 2) * 256 + tid];
      float w3 = W[(kc * 4 + 3) * 256 + tid];
      #pragma unroll
      for (int m = 0; m < 64; ++m) {
        float4v hv = *(const float4v*)&hh[m * 256 + kc * 4];
        acc[m] = fmaf(hv.w, w3, fmaf(hv.z, w2,
                 fmaf(hv.y, w1, fmaf(hv.x, w0, acc[m]))));
      }
    }
    __syncthreads();
    #pragma unroll
    for (int m = 0; m < 64; ++m)
      hh[m * 256 + tid] = LN2 * softplus_hat(acc[m] * LOG2E);
    __syncthreads();
  }
  {
    const int m = tid >> 2, qq = tid & 3;
    const float* wv = Wout + (s << 8);
    float sum = 0.f;
    for (int i = 0; i < 16; ++i) {
      int kk = (qq << 6) + ((((tid & 15) + i) << 2) & 63);
      float4v hv = *(const float4v*)&hh[m * 256 + kk];
      sum += hv.x * wv[kk] + hv.y * wv[kk + 1] + hv.z * wv[kk + 2] + hv.w * wv[kk + 3];
    }
    red[tid] = sum;
    __syncthreads();
    if (tid < 64)
      out[(m0 + tid) * 8 + s] =
          red[tid * 4] + red[tid * 4 + 1] + red[tid * 4 + 2] + red[tid * 4 + 3] + bout[s];
  }
}

extern "C" void kernel_launch(void* const* d_in, const int* in_sizes, int n_in,
                              void* d_out, int out_size, void* d_ws, size_t ws_size,
                              hipStream_t stream) {
  const float* coords = (const float*)d_in[0];
  const float* W0     = (const float*)d_in[1];
  const float* b0     = (const float*)d_in[2];
  const float* Wh     = (const float*)d_in[3];
  const float* bh     = (const float*)d_in[4];
  const float* Wout   = (const float*)d_in[5];
  const float* bout   = (const float*)d_in[6];
  float* out = (float*)d_out;

  const size_t WT_BYTES = (size_t)8 * 4 * 256 * 256 * 2;   // 4 MiB bf16 slabs
  if (ws_size >= WT_BYTES) {
    unsigned short* Wt = (unsigned short*)d_ws;
    convert_wh<<<8192, 256, 0, stream>>>(Wh, Wt);
    // 1563 m-blocks x 128 rows x 8 series; 1562*128+64 = 200000 (tail tile1 dead)
    series_mlp<<<dim3(12504), dim3(256), 0, stream>>>(
        coords, W0, b0, bh, Wout, bout, Wt, out);
  } else {
    series_mlp_slow<<<dim3(3125, 8), dim3(256), 0, stream>>>(
        coords, W0, b0, Wh, bh, Wout, bout, out);
  }
  // second tuple output: echo coords
  hipMemcpyAsync(out + (size_t)200000 * 8, coords,
                 (size_t)200000 * 3 * sizeof(float),
                 hipMemcpyDeviceToDevice, stream);
}